// Round 14
// baseline (501.821 us; speedup 1.0000x reference)
//
#include <hip/hip_runtime.h>
#include <hip/hip_bf16.h>
#include <stdint.h>

#define D_H 128

typedef __bf16 bf16_t;
typedef unsigned short u16;
typedef bf16_t bf16x8 __attribute__((ext_vector_type(8)));
typedef bf16_t bf16x4 __attribute__((ext_vector_type(4)));
typedef float  f32x4  __attribute__((ext_vector_type(4)));

#define MAINB 1024   // main pipeline blocks (co-resident: 4 waves each, <=2048 cap)

// software grid barrier among the MAINB main blocks (all co-resident)
static __device__ __forceinline__ void gridbar(int* ctr, int target) {
    __syncthreads();
    if (threadIdx.x == 0) {
        __threadfence();
        atomicAdd(ctr, 1);
        while (atomicAdd(ctr, 0) < target) { }
        __threadfence();
    }
    __syncthreads();
}

// ---- fused pre-pass: countrank + full exclusive scan + offc + dis + W prep --
// blocks [0, MAINB): phase1 grid-stride 4-way privatized countrank;
//   BAR; phase2 per-block scan of 256 nodes; BAR; phase3 block0 scans the
//   1024 block totals; BAR; phase4 finalize off/offc (+ off[N]=E).
// blocks [MAINB, ...): W1/W2 transpose + hi/lo split (no barrier participation).
__global__ __launch_bounds__(256) void k_prescan(
        const int* __restrict__ dst, int* __restrict__ cnt4,
        u16* __restrict__ rank, int E, int N,
        int* __restrict__ bars, int* __restrict__ bsums,
        int* __restrict__ off, int* __restrict__ offc, float* __restrict__ dis,
        const float* __restrict__ W1, bf16_t* __restrict__ W1h,
        bf16_t* __restrict__ W1l, int K1,
        const float* __restrict__ W2, bf16_t* __restrict__ W2h,
        bf16_t* __restrict__ W2l, int K2, int scanBlks) {
    const int bx = (int)blockIdx.x;
    const int t  = threadIdx.x;

    if (bx >= MAINB) {                       // ---- weight prep blocks ----
        int id = (bx - MAINB) * 256 + t;
        int n1 = K1 * 128;
        if (id < n1) {
            int k = id >> 7, n = id & 127;
            float w = W1[id];
            bf16_t h = (bf16_t)w;
            W1h[(size_t)n * K1 + k] = h;
            W1l[(size_t)n * K1 + k] = (bf16_t)(w - (float)h);
        } else if (id < n1 + K2 * 128) {
            int id2 = id - n1;
            int k = id2 >> 7, n = id2 & 127;
            float w = W2[id2];
            bf16_t h = (bf16_t)w;
            W2h[(size_t)n * K2 + k] = h;
            W2l[(size_t)n * K2 + k] = (bf16_t)(w - (float)h);
        }
        return;
    }

    // ---- phase 1: countrank (grid-stride; copy keyed to 256-edge chunk) ----
    for (int e = bx * 256 + t; e < E; e += MAINB * 256) {
        int d = dst[e];
        int copy = (e >> 8) & 3;
        rank[e] = (u16)atomicAdd(&cnt4[copy * N + d], 1);
    }
    gridbar(&bars[0], MAINB);

    // ---- phase 2: per-block scan over 256 nodes ----
    __shared__ int tmp[256];
    const int node = bx * 256 + t;
    int v = 0, c0 = 0, c1 = 0, c2 = 0;
    if (bx < scanBlks && node < N) {
        c0 = cnt4[node];
        c1 = cnt4[N + node];
        c2 = cnt4[2 * N + node];
        int c3 = cnt4[3 * N + node];
        v = c0 + c1 + c2 + c3;
        dis[node] = 1.0f / sqrtf((float)(v + 1));
    }
    tmp[t] = v;
    __syncthreads();
    for (int d = 1; d < 256; d <<= 1) {
        int x = (t >= d) ? tmp[t - d] : 0;
        __syncthreads();
        tmp[t] += x;
        __syncthreads();
    }
    const int excl = tmp[t] - v;
    if (t == 255) bsums[bx] = tmp[255];
    gridbar(&bars[1], MAINB);

    // ---- phase 3: block 0 exclusive-scans the 1024 block totals ----
    if (bx == 0) {
        int b0 = bsums[t * 4 + 0], b1 = bsums[t * 4 + 1];
        int b2 = bsums[t * 4 + 2], b3 = bsums[t * 4 + 3];
        int s = b0 + b1 + b2 + b3;
        tmp[t] = s;
        __syncthreads();
        for (int d = 1; d < 256; d <<= 1) {
            int x = (t >= d) ? tmp[t - d] : 0;
            __syncthreads();
            tmp[t] += x;
            __syncthreads();
        }
        int ex = tmp[t] - s;
        bsums[t * 4 + 0] = ex;
        bsums[t * 4 + 1] = ex + b0;
        bsums[t * 4 + 2] = ex + b0 + b1;
        bsums[t * 4 + 3] = ex + b0 + b1 + b2;
    }
    gridbar(&bars[2], MAINB);

    // ---- phase 4: finalize off / offc ----
    if (bx < scanBlks && node < N) {
        int o = bsums[bx] + excl;
        off[node]        = o;
        offc[node]       = o;
        offc[N + node]   = o + c0;
        offc[2 * N + node] = o + c0 + c1;
        offc[3 * N + node] = o + c0 + c1 + c2;
    }
    if (bx == 0 && t == 0) off[N] = E;
}

// ---------------- MFMA GEMM tiles: BM=64, BN=64, 256 thr = 4 waves --------
// Round-8 structure (best measured). blockIdx: row0=(bx>>1)*64, col0=(bx&1)*64.
#define LDK 40
#define FILL_PER 2

// layer-1 (fp32 A, hi/lo split in-kernel) + distributed atomic-free CSR fill
__global__ __launch_bounds__(256) void k_mm1fill(
        const float* __restrict__ Af,
        const bf16_t* __restrict__ Wh, const bf16_t* __restrict__ Wl,
        const float* __restrict__ dis, bf16_t* __restrict__ Cb,
        int N, int K,
        const int* __restrict__ src, const int* __restrict__ dst,
        const int* __restrict__ offc, const u16* __restrict__ rank,
        u16* __restrict__ csr16, int E, int totThreads) {
    __shared__ bf16_t AsH[64][LDK];
    __shared__ bf16_t AsL[64][LDK];
    __shared__ bf16_t BsH[64][LDK];
    __shared__ bf16_t BsL[64][LDK];

    const int t    = threadIdx.x;
    const int lane = t & 63;
    const int wave = t >> 6;            // 0..3
    const int row0 = ((int)blockIdx.x >> 1) * 64;
    const int col0 = ((int)blockIdx.x & 1) * 64;
    const int wm   = (wave & 1) * 32;
    const int wn   = (wave >> 1) * 32;
    const int fm   = lane & 15;
    const int fq   = lane >> 4;

    // ---- fill prologue: resolve scatter addresses (copy keyed to e>>8) ----
    const int g = (int)blockIdx.x * 256 + t;
    int epos[FILL_PER];
    u16 esrc[FILL_PER];
#pragma unroll
    for (int i = 0; i < FILL_PER; i++) {
        int e = g + i * totThreads;
        if (e < E) {
            int d    = dst[e];
            int copy = (e >> 8) & 3;
            epos[i] = offc[copy * N + d] + (int)rank[e];
            esrc[i] = (u16)src[e];
        } else {
            epos[i] = -1;
            esrc[i] = 0;
        }
    }

    f32x4 acc[2][2] = {};

    for (int k0 = 0; k0 < K; k0 += 32) {
        __syncthreads();
        // stage A: 64 rows x 32 k fp32 = 512 float4; 2/thread, split hi/lo
#pragma unroll
        for (int i = 0; i < 2; i++) {
            int idx = t + i * 256;
            int r   = idx >> 3;
            int c4  = idx & 7;
            int gr  = row0 + r;
            float4 v = make_float4(0.f, 0.f, 0.f, 0.f);
            if (gr < N) v = *(const float4*)(Af + (size_t)gr * K + k0 + c4 * 4);
            bf16_t h0 = (bf16_t)v.x, h1 = (bf16_t)v.y, h2 = (bf16_t)v.z, h3 = (bf16_t)v.w;
            bf16_t l0 = (bf16_t)(v.x - (float)h0);
            bf16_t l1 = (bf16_t)(v.y - (float)h1);
            bf16_t l2 = (bf16_t)(v.z - (float)h2);
            bf16_t l3 = (bf16_t)(v.w - (float)h3);
            *(bf16x4*)&AsH[r][c4 * 4] = (bf16x4){h0, h1, h2, h3};
            *(bf16x4*)&AsL[r][c4 * 4] = (bf16x4){l0, l1, l2, l3};
        }
        // stage B: 64 cols x 32 k; 1/thread per plane
        {
            int r  = t >> 2;
            int c8 = t & 3;
            *(bf16x8*)&BsH[r][c8 * 8] = *(const bf16x8*)(Wh + (size_t)(col0 + r) * K + k0 + c8 * 8);
            *(bf16x8*)&BsL[r][c8 * 8] = *(const bf16x8*)(Wl + (size_t)(col0 + r) * K + k0 + c8 * 8);
        }
        __syncthreads();

        bf16x8 ah[2], al[2], bh[2], bl[2];
#pragma unroll
        for (int i = 0; i < 2; i++) {
            ah[i] = *(const bf16x8*)&AsH[wm + i * 16 + fm][fq * 8];
            al[i] = *(const bf16x8*)&AsL[wm + i * 16 + fm][fq * 8];
            bh[i] = *(const bf16x8*)&BsH[wn + i * 16 + fm][fq * 8];
            bl[i] = *(const bf16x8*)&BsL[wn + i * 16 + fm][fq * 8];
        }
#pragma unroll
        for (int mi = 0; mi < 2; mi++)
#pragma unroll
            for (int ni = 0; ni < 2; ni++) {
                acc[mi][ni] = __builtin_amdgcn_mfma_f32_16x16x32_bf16(ah[mi], bh[ni], acc[mi][ni], 0, 0, 0);
                acc[mi][ni] = __builtin_amdgcn_mfma_f32_16x16x32_bf16(ah[mi], bl[ni], acc[mi][ni], 0, 0, 0);
                acc[mi][ni] = __builtin_amdgcn_mfma_f32_16x16x32_bf16(al[mi], bh[ni], acc[mi][ni], 0, 0, 0);
            }
    }

#pragma unroll
    for (int mi = 0; mi < 2; mi++)
#pragma unroll
        for (int r = 0; r < 4; r++) {
            int grow = row0 + wm + mi * 16 + fq * 4 + r;
            if (grow < N) {
                float dr = dis[grow];
#pragma unroll
                for (int ni = 0; ni < 2; ni++)
                    Cb[(size_t)grow * D_H + col0 + wn + ni * 16 + fm] = (bf16_t)(dr * acc[mi][ni][r]);
            }
        }

    // ---- fill epilogue: scattered 2B stores, fire and forget ----
#pragma unroll
    for (int i = 0; i < FILL_PER; i++)
        if (epos[i] >= 0) csr16[epos[i]] = esrc[i];
}

// layer-2 (bf16 hi/lo A), round-8 structure
__global__ __launch_bounds__(256) void k_mm2(const bf16_t* __restrict__ Ah,
                                             const bf16_t* __restrict__ Al,
                                             const bf16_t* __restrict__ Wh,
                                             const bf16_t* __restrict__ Wl,
                                             const float* __restrict__ dis,
                                             bf16_t* __restrict__ Cb,
                                             int N, int K) {
    __shared__ bf16_t AsH[64][LDK];
    __shared__ bf16_t AsL[64][LDK];
    __shared__ bf16_t BsH[64][LDK];
    __shared__ bf16_t BsL[64][LDK];

    const int t    = threadIdx.x;
    const int lane = t & 63;
    const int wave = t >> 6;
    const int row0 = ((int)blockIdx.x >> 1) * 64;
    const int col0 = ((int)blockIdx.x & 1) * 64;
    const int wm   = (wave & 1) * 32;
    const int wn   = (wave >> 1) * 32;
    const int fm   = lane & 15;
    const int fq   = lane >> 4;

    f32x4 acc[2][2] = {};

    for (int k0 = 0; k0 < K; k0 += 32) {
        __syncthreads();
        {
            int r  = t >> 2;
            int c8 = t & 3;
            int gr = row0 + r;
            bf16x8 vh = {}, vl = {};
            if (gr < N) {
                vh = *(const bf16x8*)(Ah + (size_t)gr * K + k0 + c8 * 8);
                vl = *(const bf16x8*)(Al + (size_t)gr * K + k0 + c8 * 8);
            }
            *(bf16x8*)&AsH[r][c8 * 8] = vh;
            *(bf16x8*)&AsL[r][c8 * 8] = vl;
            *(bf16x8*)&BsH[r][c8 * 8] = *(const bf16x8*)(Wh + (size_t)(col0 + r) * K + k0 + c8 * 8);
            *(bf16x8*)&BsL[r][c8 * 8] = *(const bf16x8*)(Wl + (size_t)(col0 + r) * K + k0 + c8 * 8);
        }
        __syncthreads();

        bf16x8 ah[2], al[2], bh[2], bl[2];
#pragma unroll
        for (int i = 0; i < 2; i++) {
            ah[i] = *(const bf16x8*)&AsH[wm + i * 16 + fm][fq * 8];
            al[i] = *(const bf16x8*)&AsL[wm + i * 16 + fm][fq * 8];
            bh[i] = *(const bf16x8*)&BsH[wn + i * 16 + fm][fq * 8];
            bl[i] = *(const bf16x8*)&BsL[wn + i * 16 + fm][fq * 8];
        }
#pragma unroll
        for (int mi = 0; mi < 2; mi++)
#pragma unroll
            for (int ni = 0; ni < 2; ni++) {
                acc[mi][ni] = __builtin_amdgcn_mfma_f32_16x16x32_bf16(ah[mi], bh[ni], acc[mi][ni], 0, 0, 0);
                acc[mi][ni] = __builtin_amdgcn_mfma_f32_16x16x32_bf16(ah[mi], bl[ni], acc[mi][ni], 0, 0, 0);
                acc[mi][ni] = __builtin_amdgcn_mfma_f32_16x16x32_bf16(al[mi], bh[ni], acc[mi][ni], 0, 0, 0);
            }
    }

#pragma unroll
    for (int mi = 0; mi < 2; mi++)
#pragma unroll
        for (int r = 0; r < 4; r++) {
            int grow = row0 + wm + mi * 16 + fq * 4 + r;
            if (grow < N) {
                float dr = dis[grow];
#pragma unroll
                for (int ni = 0; ni < 2; ni++)
                    Cb[(size_t)grow * D_H + col0 + wn + ni * 16 + fm] = (bf16_t)(dr * acc[mi][ni][r]);
            }
        }
}

// ---------------- aggregation (16 lanes/node x bf16x8 = 16B/lane) ----------
__global__ __launch_bounds__(256) void k_agg(const bf16_t* __restrict__ Hb,
                                             const float* __restrict__ dis,
                                             const int* __restrict__ off,
                                             const u16* __restrict__ csr16,
                                             const float4* __restrict__ bias4,
                                             float4* __restrict__ outF,
                                             bf16_t* __restrict__ outH,
                                             bf16_t* __restrict__ outL,
                                             int N, int mode) {
    const int slot = threadIdx.x >> 4;           // 0..15: node slot
    const int lane = threadIdx.x & 15;           // feature group (8 bf16 = 16B)
    const int node = blockIdx.x * 16 + slot;
    if (node >= N) return;

    const bf16_t* Hrow = Hb + (size_t)lane * 8;

    float a0[8], a1[8], a2[8], a3[8];
    {
        bf16x8 v = *(const bf16x8*)(Hrow + (size_t)node * D_H);
#pragma unroll
        for (int j = 0; j < 8; j++) { a0[j] = (float)v[j]; a1[j] = 0.f; a2[j] = 0.f; a3[j] = 0.f; }
    }

    int p  = off[node];
    int p1 = off[node + 1];

    for (; p + 4 <= p1; p += 4) {
        int s0 = (int)csr16[p + 0], s1 = (int)csr16[p + 1];
        int s2 = (int)csr16[p + 2], s3 = (int)csr16[p + 3];
        bf16x8 h0 = *(const bf16x8*)(Hrow + (size_t)s0 * D_H);
        bf16x8 h1 = *(const bf16x8*)(Hrow + (size_t)s1 * D_H);
        bf16x8 h2 = *(const bf16x8*)(Hrow + (size_t)s2 * D_H);
        bf16x8 h3 = *(const bf16x8*)(Hrow + (size_t)s3 * D_H);
#pragma unroll
        for (int j = 0; j < 8; j++) {
            a0[j] += (float)h0[j];
            a1[j] += (float)h1[j];
            a2[j] += (float)h2[j];
            a3[j] += (float)h3[j];
        }
    }
    if (p + 2 <= p1) {
        int s0 = (int)csr16[p + 0], s1 = (int)csr16[p + 1];
        bf16x8 h0 = *(const bf16x8*)(Hrow + (size_t)s0 * D_H);
        bf16x8 h1 = *(const bf16x8*)(Hrow + (size_t)s1 * D_H);
#pragma unroll
        for (int j = 0; j < 8; j++) { a0[j] += (float)h0[j]; a1[j] += (float)h1[j]; }
        p += 2;
    }
    if (p < p1) {
        int s0 = (int)csr16[p];
        bf16x8 h0 = *(const bf16x8*)(Hrow + (size_t)s0 * D_H);
#pragma unroll
        for (int j = 0; j < 8; j++) a2[j] += (float)h0[j];
    }

    float sum[8];
#pragma unroll
    for (int j = 0; j < 8; j++) sum[j] = (a0[j] + a1[j]) + (a2[j] + a3[j]);

    const float  di = dis[node];
    const float4 b0 = bias4[lane * 2];
    const float4 b1 = bias4[lane * 2 + 1];
    float v0 = fmaf(di, sum[0], b0.x), v1 = fmaf(di, sum[1], b0.y);
    float v2 = fmaf(di, sum[2], b0.z), v3 = fmaf(di, sum[3], b0.w);
    float v4 = fmaf(di, sum[4], b1.x), v5 = fmaf(di, sum[5], b1.y);
    float v6 = fmaf(di, sum[6], b1.z), v7 = fmaf(di, sum[7], b1.w);

    if (mode == 1) {
        v0 = fmaxf(v0, 0.f); v1 = fmaxf(v1, 0.f); v2 = fmaxf(v2, 0.f); v3 = fmaxf(v3, 0.f);
        v4 = fmaxf(v4, 0.f); v5 = fmaxf(v5, 0.f); v6 = fmaxf(v6, 0.f); v7 = fmaxf(v7, 0.f);
        bf16_t h0 = (bf16_t)v0, h1 = (bf16_t)v1, h2 = (bf16_t)v2, h3 = (bf16_t)v3;
        bf16_t h4 = (bf16_t)v4, h5 = (bf16_t)v5, h6 = (bf16_t)v6, h7 = (bf16_t)v7;
        *(bf16x8*)(outH + (size_t)node * D_H + lane * 8) =
            (bf16x8){h0, h1, h2, h3, h4, h5, h6, h7};
        *(bf16x8*)(outL + (size_t)node * D_H + lane * 8) =
            (bf16x8){(bf16_t)(v0 - (float)h0), (bf16_t)(v1 - (float)h1),
                     (bf16_t)(v2 - (float)h2), (bf16_t)(v3 - (float)h3),
                     (bf16_t)(v4 - (float)h4), (bf16_t)(v5 - (float)h5),
                     (bf16_t)(v6 - (float)h6), (bf16_t)(v7 - (float)h7)};
    } else {
        outF[(size_t)node * 32 + lane * 2]     = make_float4(v0, v1, v2, v3);
        outF[(size_t)node * 32 + lane * 2 + 1] = make_float4(v4, v5, v6, v7);
    }
}

extern "C" void kernel_launch(void* const* d_in, const int* in_sizes, int n_in,
                              void* d_out, int out_size, void* d_ws, size_t ws_size,
                              hipStream_t stream) {
    const float* X  = (const float*)d_in[0];
    const int*   ei = (const int*)d_in[1];
    const float* W1 = (const float*)d_in[2];
    const float* b1 = (const float*)d_in[3];
    const float* W2 = (const float*)d_in[4];
    const float* b2 = (const float*)d_in[5];
    float* out = (float*)d_out;

    const int N  = in_sizes[0] / 256;   // 50000
    const int E  = in_sizes[1] / 2;     // 800000
    const int K1 = 256;

    const int* src = ei;
    const int* dst = ei + E;

    uintptr_t p = (uintptr_t)d_ws;
    auto carve = [&](size_t bytes) {
        uintptr_t q = p;
        p += (bytes + 255) & ~(size_t)255;
        return q;
    };
    int*    cnt4  = (int*)carve((size_t)N * 4 * 4);     // 4 privatized copies
    int*    bars  = (int*)carve(256);                   // 3 grid-barrier ctrs (zeroed w/ cnt4)
    int*    off   = (int*)carve((size_t)(N + 1) * 4);
    int*    offc  = (int*)carve((size_t)N * 4 * 4);     // per-copy bases
    int*    bsums = (int*)carve(MAINB * 4);
    float*  dis   = (float*)carve((size_t)N * 4);
    u16*    rank  = (u16*)carve((size_t)E * 2);
    u16*    csr16 = (u16*)carve((size_t)E * 2);
    bf16_t* Hb    = (bf16_t*)carve((size_t)N * D_H * 2);
    bf16_t* X1h   = (bf16_t*)carve((size_t)N * D_H * 2);
    bf16_t* X1l   = (bf16_t*)carve((size_t)N * D_H * 2);
    bf16_t* W1h   = (bf16_t*)carve((size_t)K1 * D_H * 2);
    bf16_t* W1l   = (bf16_t*)carve((size_t)K1 * D_H * 2);
    bf16_t* W2h   = (bf16_t*)carve((size_t)D_H * D_H * 2);
    bf16_t* W2l   = (bf16_t*)carve((size_t)D_H * D_H * 2);

    // one memset covers cnt4 (N*16, 256-aligned) + bars
    hipMemsetAsync(cnt4, 0, (((size_t)N * 16 + 255) & ~(size_t)255) + 256, stream);

    // fused pre-pass: countrank + scans + offc + dis + weight prep (1 dispatch)
    const int gw       = (K1 * 128 + D_H * 128 + 255) / 256;   // 192 W-prep blocks
    const int scanBlks = (N + 255) / 256;
    k_prescan<<<MAINB + gw, 256, 0, stream>>>(dst, cnt4, rank, E, N,
                                              bars, bsums, off, offc, dis,
                                              W1, W1h, W1l, K1,
                                              W2, W2h, W2l, D_H, scanBlks);

    const int gmm = ((N + 63) / 64) * 2;    // 1564 blocks (row x col split)
    const int gag = (N + 15) / 16;          // 3125 agg blocks

    // layer 1 GEMM (round-8 structure) with distributed atomic-free CSR fill
    k_mm1fill<<<gmm, 256, 0, stream>>>(X, W1h, W1l, dis, Hb, N, K1,
                                       src, dst, offc, rank, csr16, E, gmm * 256);
    k_agg<<<gag, 256, 0, stream>>>(Hb, dis, off, csr16,
                                   (const float4*)b1, nullptr, X1h, X1l, N, 1);

    // layer 2
    k_mm2<<<gmm, 256, 0, stream>>>(X1h, X1l, W2h, W2l, dis, Hb, N, D_H);
    k_agg<<<gag, 256, 0, stream>>>(Hb, dis, off, csr16,
                                   (const float4*)b2, (float4*)out, nullptr, nullptr, N, 0);
}